// Round 5
// baseline (339.338 us; speedup 1.0000x reference)
//
#include <hip/hip_runtime.h>

// MomentumLora v3c (resubmit; source-hash bump only — semantics identical to v3/v3b).
// out[M,2304] = x[M,768] @ (concat(Aq@Bq, Ak@Bk, Av@Bv) * 1/16)
// Factored:  y[M,48] = (x @ [Aq|Ak|Av]) * s     (stage 1, split-K)
//            out[:, z*768:(z+1)*768] = y[:, z*16:(z+1)*16] @ B_z   (stage 2)
// M = 128*197 = 25216, dim = 768, r = 16, s = 1/16.
//
// ** No d_ws. ** y-partials live in the last NSPLIT*48 = 192 columns of out
// (out[:, 2112:2304]). Race-free because stage2 assigns ONE block per 64-row
// tile: it reduces the partials for its rows into LDS (barrier) before
// overwriting any column of those rows, and no other block touches them.
// (Workspace re-poison fill = 4*out_size = 929 MB @ ~139 us/iter was inside
//  the timed graph; dropping d_ws is the experiment.)

#define DIM     768
#define RNK     16
#define NCOLS   48
#define OUTC    2304
#define NSPLIT  4
#define KSPAN   192           // DIM / NSPLIT
#define SCRATCH0 2112         // OUTC - NSPLIT*NCOLS
#define XS_STRIDE 52          // 48 + 4 pad (16B-aligned rows, bank-spread)

typedef float f32x4 __attribute__((ext_vector_type(4)));

// ---------------- Stage 1: out[:, 2112+sp*48 : +48] = x-slice @ Acat ----------------
// 192 threads (3 waves). Tile: 128 rows x 48 cols, K chunks of 48, kspan=192.
// Thread = (rg 0..15, cg 0..11): owns rows rg+16i (i<8), cols 4cg..4cg+3.
__global__ __launch_bounds__(192) void lora_stage1(
    const float* __restrict__ x,
    const float* __restrict__ Aq, const float* __restrict__ Ak,
    const float* __restrict__ Av,
    const int* __restrict__ depth_id,
    float* __restrict__ out)
{
    __shared__ float xs[128 * XS_STRIDE];   // 26.6 KB
    __shared__ float as[48 * NCOLS];        //  9.2 KB

    const int t  = threadIdx.x;
    const int rg = t / 12;
    const int cg = t % 12;
    const int row0  = blockIdx.x * 128;
    const int spl   = blockIdx.y;
    const int kbase = spl * KSPAN;

    const int dep = depth_id[0];
    const size_t aoff = (size_t)dep * DIM * RNK;
    const float* Ab0 = Aq + aoff;
    const float* Ab1 = Ak + aoff;
    const float* Ab2 = Av + aoff;

    f32x4 acc[8] = {};   // acc[i] = 4 cols for row rg+16i

    for (int kc = 0; kc < KSPAN; kc += 48) {
        const int k0 = kbase + kc;
        // stage x tile: 128 rows x 48 k  (1536 float4s, nontemporal)
        #pragma unroll
        for (int j = 0; j < 8; j++) {
            const int f = t + j * 192;
            const int r = f / 12, k4 = f % 12;
            const f32x4 v = __builtin_nontemporal_load(
                reinterpret_cast<const f32x4*>(&x[(size_t)(row0 + r) * DIM + k0 + 4 * k4]));
            *reinterpret_cast<f32x4*>(&xs[r * XS_STRIDE + 4 * k4]) = v;
        }
        // stage A tile: 48 k x 48 cols (q|k|v col-major groups)
        #pragma unroll
        for (int j = 0; j < 3; j++) {
            const int f = t + j * 192;
            const int k = f / 12, c4 = f % 12;
            const int z = c4 >> 2, cq = c4 & 3;
            const float* Ap = (z == 0) ? Ab0 : ((z == 1) ? Ab1 : Ab2);
            const f32x4 v = *reinterpret_cast<const f32x4*>(&Ap[(size_t)(k0 + k) * RNK + 4 * cq]);
            *reinterpret_cast<f32x4*>(&as[k * NCOLS + 4 * c4]) = v;
        }
        __syncthreads();

        #pragma unroll 2
        for (int kk = 0; kk < 48; kk += 4) {
            f32x4 xf[8], af[4];
            #pragma unroll
            for (int i = 0; i < 8; i++)
                xf[i] = *reinterpret_cast<const f32x4*>(&xs[(rg + 16 * i) * XS_STRIDE + kk]);
            #pragma unroll
            for (int j = 0; j < 4; j++)
                af[j] = *reinterpret_cast<const f32x4*>(&as[(kk + j) * NCOLS + 4 * cg]);
            #pragma unroll
            for (int i = 0; i < 8; i++) {
                acc[i] += xf[i][0] * af[0];
                acc[i] += xf[i][1] * af[1];
                acc[i] += xf[i][2] * af[2];
                acc[i] += xf[i][3] * af[3];
            }
        }
        __syncthreads();
    }

    const float s = 0.0625f;
    #pragma unroll
    for (int i = 0; i < 8; i++) {
        f32x4 v = acc[i] * s;
        // partial sp for row r lives at out[r, 2112 + sp*48 + c]  (plain store: L2-resident for stage2)
        *reinterpret_cast<f32x4*>(
            &out[(size_t)(row0 + rg + 16 * i) * OUTC + SCRATCH0 + spl * NCOLS + 4 * cg]) = v;
    }
}

// ---------------- Stage 2: one block per 64-row tile, loops 9 x 256-col chunks ----------------
// 256 threads (4 waves). Gathers y-partials from out[:,2112:2304] -> Ys[64][48] (reduced),
// then per chunk: B panel global->reg (L2-hot, 147 KB total), 16 rows/wave, f32x4/lane.
__global__ __launch_bounds__(256) void lora_stage2(
    const float* __restrict__ Bq, const float* __restrict__ Bk,
    const float* __restrict__ Bv,
    const int* __restrict__ depth_id,
    float* out)   // NOT restrict: reads scratch + writes final through same pointer
{
    __shared__ float Ys[64 * NCOLS];   // 12 KB, reduced y for this row tile

    const int t    = threadIdx.x;
    const int row0 = blockIdx.x * 64;

    // gather + reduce split-K partials: 64 rows x 12 f32x4 = 768 gathers, 3/thread
    #pragma unroll
    for (int j = 0; j < 3; j++) {
        const int f = t + j * 256;
        const int r = f / 12, q4 = f % 12;
        const size_t base = (size_t)(row0 + r) * OUTC + SCRATCH0 + 4 * q4;
        f32x4 a = *reinterpret_cast<const f32x4*>(&out[base]);
        #pragma unroll
        for (int sp = 1; sp < NSPLIT; sp++)
            a += *reinterpret_cast<const f32x4*>(&out[base + sp * NCOLS]);
        *reinterpret_cast<f32x4*>(&Ys[r * NCOLS + 4 * q4]) = a;
    }
    __syncthreads();   // all partials of this row tile are in LDS; scratch may now be clobbered

    const int dep = depth_id[0];
    const int w   = t >> 6;
    const int c4  = t & 63;

    for (int chunk = 0; chunk < 9; chunk++) {
        const int z    = chunk / 3;             // 0,1,2
        const int c0z  = (chunk - 3 * z) * 256; // col within the z-panel
        const int col0 = z * DIM + c0z;
        const float* Bz = ((z == 0) ? Bq : ((z == 1) ? Bk : Bv)) + (size_t)dep * RNK * DIM;

        // B column slice straight to registers (coalesced, L2-resident)
        f32x4 bk[16];
        #pragma unroll
        for (int k = 0; k < 16; k++)
            bk[k] = *reinterpret_cast<const f32x4*>(&Bz[(size_t)k * DIM + c0z + 4 * c4]);

        #pragma unroll 2
        for (int i = 0; i < 16; i++) {
            const int r = 16 * w + i;
            const float* yr = &Ys[r * NCOLS + z * RNK];
            const f32x4 y0 = *reinterpret_cast<const f32x4*>(&yr[0]);
            const f32x4 y1 = *reinterpret_cast<const f32x4*>(&yr[4]);
            const f32x4 y2 = *reinterpret_cast<const f32x4*>(&yr[8]);
            const f32x4 y3 = *reinterpret_cast<const f32x4*>(&yr[12]);
            f32x4 acc = y0[0] * bk[0];
            acc += y0[1] * bk[1];  acc += y0[2] * bk[2];  acc += y0[3] * bk[3];
            acc += y1[0] * bk[4];  acc += y1[1] * bk[5];  acc += y1[2] * bk[6];  acc += y1[3] * bk[7];
            acc += y2[0] * bk[8];  acc += y2[1] * bk[9];  acc += y2[2] * bk[10]; acc += y2[3] * bk[11];
            acc += y3[0] * bk[12]; acc += y3[1] * bk[13]; acc += y3[2] * bk[14]; acc += y3[3] * bk[15];
            __builtin_nontemporal_store(acc,
                reinterpret_cast<f32x4*>(&out[(size_t)(row0 + r) * OUTC + col0 + 4 * c4]));
        }
    }
}

extern "C" void kernel_launch(void* const* d_in, const int* in_sizes, int n_in,
                              void* d_out, int out_size, void* d_ws, size_t ws_size,
                              hipStream_t stream) {
    const float* x  = (const float*)d_in[0];
    const float* Aq = (const float*)d_in[1];
    const float* Bq = (const float*)d_in[2];
    const float* Ak = (const float*)d_in[3];
    const float* Bk = (const float*)d_in[4];
    const float* Av = (const float*)d_in[5];
    const float* Bv = (const float*)d_in[6];
    const int* dep  = (const int*)d_in[7];
    float* out = (float*)d_out;
    (void)d_ws; (void)ws_size;   // workspace intentionally untouched

    const int M = in_sizes[0] / DIM;  // 25216 = 128 * 197

    lora_stage1<<<dim3(M / 128, NSPLIT), 192, 0, stream>>>(x, Aq, Ak, Av, dep, out);
    lora_stage2<<<dim3(M / 64), 256, 0, stream>>>(Bq, Bk, Bv, dep, out);
}

// Round 6
// 328.857 us; speedup vs baseline: 1.0319x; 1.0319x over previous
//
#include <hip/hip_runtime.h>

// MomentumLora v4: out[M,2304] = x[M,768] @ (concat(Aq@Bq, Ak@Bk, Av@Bv) * 1/16)
// Stage 1: ypart[sp][M][48] = x[:, sp*192:(sp+1)*192] @ Acat-slice   (split-K=4, d_ws)
// Stage 2: out[64-row, 256-col tile] = (sum_sp ypart)[:, z*16:+16] @ B_z panel
// ws poison fill (929 MB, ~150 us) is UNCONDITIONAL (R5 evidence) -> d_ws is free.
// v4 change: stage1 tile 128->64 rows: grid (394,4)=1576 blocks, 22.5 KB LDS
// -> ~6 blocks/CU resident (was 2.3 waves/SIMD) to fix latency-bound stage1.

#define DIM   768
#define RNK   16
#define NCOLS 48
#define OUTC  2304
#define XS_STRIDE 52   // 48 + 4 pad

typedef float f32x4 __attribute__((ext_vector_type(4)));

// ---------------- Stage 1: 64 rows x 48 cols, K chunks of 48 ----------------
// 192 threads (3 waves). Thread (rg 0..15, cg 0..11): rows rg+16i (i<4), cols 4cg..+3.
__global__ __launch_bounds__(192) void lora_stage1(
    const float* __restrict__ x,
    const float* __restrict__ Aq, const float* __restrict__ Ak,
    const float* __restrict__ Av,
    const int* __restrict__ depth_id,
    float* __restrict__ ypart, int kspan, int M)
{
    __shared__ float xs[64 * XS_STRIDE];   // 13.3 KB
    __shared__ float as[48 * NCOLS];       //  9.2 KB

    const int t  = threadIdx.x;
    const int rg = t / 12;
    const int cg = t % 12;
    const int row0  = blockIdx.x * 64;
    const int kbase = blockIdx.y * kspan;

    const int dep = depth_id[0];
    const size_t aoff = (size_t)dep * DIM * RNK;
    const float* Ab0 = Aq + aoff;
    const float* Ab1 = Ak + aoff;
    const float* Ab2 = Av + aoff;

    f32x4 acc[4] = {};   // acc[i] = 4 cols for row rg+16i

    for (int kc = 0; kc < kspan; kc += 48) {
        const int k0 = kbase + kc;
        // stage x tile: 64 rows x 48 k = 768 float4s, 4/thread
        #pragma unroll
        for (int j = 0; j < 4; j++) {
            const int f = t + j * 192;
            const int r = f / 12, k4 = f % 12;
            const f32x4 v = __builtin_nontemporal_load(
                reinterpret_cast<const f32x4*>(&x[(size_t)(row0 + r) * DIM + k0 + 4 * k4]));
            *reinterpret_cast<f32x4*>(&xs[r * XS_STRIDE + 4 * k4]) = v;
        }
        // stage A tile: 48 k x 48 cols; j = z panel (one array per iter, coalesced
        // 64B runs: lane t -> row k=t/4, rank-quad cq=t%4)
        #pragma unroll
        for (int j = 0; j < 3; j++) {
            const int k = t >> 2, cq = t & 3;
            const float* Ap = (j == 0) ? Ab0 : ((j == 1) ? Ab1 : Ab2);
            const f32x4 v = *reinterpret_cast<const f32x4*>(&Ap[(size_t)(k0 + k) * RNK + 4 * cq]);
            *reinterpret_cast<f32x4*>(&as[k * NCOLS + j * 16 + 4 * cq]) = v;
        }
        __syncthreads();

        #pragma unroll 4
        for (int kk = 0; kk < 48; kk += 4) {
            f32x4 xf[4], af[4];
            #pragma unroll
            for (int i = 0; i < 4; i++)
                xf[i] = *reinterpret_cast<const f32x4*>(&xs[(rg + 16 * i) * XS_STRIDE + kk]);
            #pragma unroll
            for (int j = 0; j < 4; j++)
                af[j] = *reinterpret_cast<const f32x4*>(&as[(kk + j) * NCOLS + 4 * cg]);
            #pragma unroll
            for (int i = 0; i < 4; i++) {
                acc[i] += xf[i][0] * af[0];
                acc[i] += xf[i][1] * af[1];
                acc[i] += xf[i][2] * af[2];
                acc[i] += xf[i][3] * af[3];
            }
        }
        __syncthreads();
    }

    const float s = 0.0625f;
    #pragma unroll
    for (int i = 0; i < 4; i++) {
        f32x4 v = acc[i] * s;
        *reinterpret_cast<f32x4*>(
            &ypart[((size_t)blockIdx.y * M + row0 + rg + 16 * i) * NCOLS + 4 * cg]) = v;
    }
}

// ---------------- Stage 2: grid (M/64, 9), 64 rows x 256 cols, K = 16 ----------------
// 256 threads (4 waves). Wave w rows 16w..16w+15; lane c4 owns col float4.
__global__ __launch_bounds__(256) void lora_stage2(
    const float* __restrict__ yp,
    const float* __restrict__ Bq, const float* __restrict__ Bk,
    const float* __restrict__ Bv,
    const int* __restrict__ depth_id,
    float* __restrict__ out, int nsplit, int M)
{
    __shared__ float Ys[64 * 16];   // 4 KB

    const int t     = threadIdx.x;
    const int row0  = blockIdx.x * 64;
    const int chunk = blockIdx.y;
    const int z     = chunk / 3;
    const int c0z   = (chunk - 3 * z) * 256;
    const int col0  = z * DIM + c0z;

    const int dep = depth_id[0];
    const float* Bz = ((z == 0) ? Bq : ((z == 1) ? Bk : Bv)) + (size_t)dep * RNK * DIM;

    // gather y slice for this z: 64 rows x 4 f32x4, 1/thread, sum split-K partials
    {
        const int r = t >> 2, q = t & 3;
        const size_t base = (size_t)(row0 + r) * NCOLS + z * RNK + 4 * q;
        f32x4 a = *reinterpret_cast<const f32x4*>(&yp[base]);
        for (int sp = 1; sp < nsplit; sp++)
            a += *reinterpret_cast<const f32x4*>(&yp[(size_t)sp * M * NCOLS + base]);
        *reinterpret_cast<f32x4*>(&Ys[r * 16 + 4 * q]) = a;
    }
    __syncthreads();

    const int w  = t >> 6;
    const int c4 = t & 63;

    f32x4 bk[16];
    #pragma unroll
    for (int k = 0; k < 16; k++)
        bk[k] = *reinterpret_cast<const f32x4*>(&Bz[(size_t)k * DIM + c0z + 4 * c4]);

    #pragma unroll 2
    for (int i = 0; i < 16; i++) {
        const int r = 16 * w + i;
        const f32x4 y0 = *reinterpret_cast<const f32x4*>(&Ys[r * 16 + 0]);
        const f32x4 y1 = *reinterpret_cast<const f32x4*>(&Ys[r * 16 + 4]);
        const f32x4 y2 = *reinterpret_cast<const f32x4*>(&Ys[r * 16 + 8]);
        const f32x4 y3 = *reinterpret_cast<const f32x4*>(&Ys[r * 16 + 12]);
        f32x4 acc = y0[0] * bk[0];
        acc += y0[1] * bk[1];  acc += y0[2] * bk[2];  acc += y0[3] * bk[3];
        acc += y1[0] * bk[4];  acc += y1[1] * bk[5];  acc += y1[2] * bk[6];  acc += y1[3] * bk[7];
        acc += y2[0] * bk[8];  acc += y2[1] * bk[9];  acc += y2[2] * bk[10]; acc += y2[3] * bk[11];
        acc += y3[0] * bk[12]; acc += y3[1] * bk[13]; acc += y3[2] * bk[14]; acc += y3[3] * bk[15];
        __builtin_nontemporal_store(acc,
            reinterpret_cast<f32x4*>(&out[(size_t)(row0 + r) * OUTC + col0 + 4 * c4]));
    }
}

extern "C" void kernel_launch(void* const* d_in, const int* in_sizes, int n_in,
                              void* d_out, int out_size, void* d_ws, size_t ws_size,
                              hipStream_t stream) {
    const float* x  = (const float*)d_in[0];
    const float* Aq = (const float*)d_in[1];
    const float* Bq = (const float*)d_in[2];
    const float* Ak = (const float*)d_in[3];
    const float* Bk = (const float*)d_in[4];
    const float* Av = (const float*)d_in[5];
    const float* Bv = (const float*)d_in[6];
    const int* dep  = (const int*)d_in[7];
    float* out = (float*)d_out;
    float* y   = (float*)d_ws;

    const int M = in_sizes[0] / DIM;  // 25216 = 128 * 197
    const size_t y_one = (size_t)M * NCOLS * sizeof(float);
    int nsplit = 1;
    if (ws_size >= 4 * y_one) nsplit = 4;
    else if (ws_size >= 2 * y_one) nsplit = 2;
    const int kspan = DIM / nsplit;   // 192 / 384 / 768, all % 48 == 0

    lora_stage1<<<dim3(M / 64, nsplit), 192, 0, stream>>>(x, Aq, Ak, Av, dep, y, kspan, M);
    lora_stage2<<<dim3(M / 64, (3 * DIM) / 256), 256, 0, stream>>>(y, Bq, Bk, Bv, dep, out, nsplit, M);
}